// Round 8
// baseline (2117.104 us; speedup 1.0000x reference)
//
#include <hip/hip_runtime.h>
#include <hip/hip_fp16.h>
#include <cmath>

// Problem constants
constexpr int B_ = 64, N_ = 50000, L_ = 8, E_ = 100000, U_ = 20000, G_ = 20000, R_ = 64, D_ = 16, C_ = 2;
constexpr int EPL_ = E_ + 3 * U_ + 8;  // padded edge slots per layer (+8 sentinel tail)
constexpr int NP1 = N_ + 1;            // nodes + zero sentinel row

// Double-buffered h, fp16: buffer q row s lives at flat row (q*NP1 + s).
// Row layout: h[row][b][d], d-contiguous; F = BC*2 float4 chunks per row.
// Parity P[li][s] (batch-independent) baked into ssrc (read rows) / wdst (write rows).

__device__ __forceinline__ float tanh_fast(float x) {
  float e = __expf(2.0f * x);
  return 1.0f - 2.0f * __builtin_amdgcn_rcpf(e + 1.0f);
}

// ---------------- CSR build (batch-independent) ----------------

__global__ __launch_bounds__(256) void hist_kernel(
    const int* __restrict__ dst_pos, int* __restrict__ cnt) {
  int e = blockIdx.x * 256 + threadIdx.x;
  int li = blockIdx.y;
  if (e >= E_) return;
  atomicAdd(&cnt[li * U_ + dst_pos[li * E_ + e]], 1);
}

__global__ __launch_bounds__(1024) void scan_kernel(
    const int* __restrict__ cnt, int* __restrict__ offs, int* __restrict__ cursor) {
  __shared__ int sums[1024];
  int li = blockIdx.x, t = threadIdx.x;
  int base = t * 20;
  int v[20];
  int s = 0;
#pragma unroll
  for (int i = 0; i < 20; ++i) {
    int idx = base + i;
    int c = (idx < U_) ? cnt[li * U_ + idx] : 0;
    v[i] = s;
    s += (c + 3) & ~3;
  }
  sums[t] = s;
  __syncthreads();
  for (int off = 1; off < 1024; off <<= 1) {
    int o = (t >= off) ? sums[t - off] : 0;
    __syncthreads();
    sums[t] += o;
    __syncthreads();
  }
  int excl = sums[t] - s;
#pragma unroll
  for (int i = 0; i < 20; ++i) {
    int idx = base + i;
    if (idx < U_) {
      offs[li * (U_ + 1) + idx] = excl + v[i];
      cursor[li * U_ + idx] = excl + v[i];
    }
  }
  if (t == 1023) offs[li * (U_ + 1) + U_] = sums[1023];
}

__global__ __launch_bounds__(256) void scatter_kernel(
    const int* __restrict__ dst_pos, const int* __restrict__ src,
    int* __restrict__ cursor, int* __restrict__ ssrc) {
  int e = blockIdx.x * 256 + threadIdx.x;
  int li = blockIdx.y;
  if (e >= E_) return;
  int u = dst_pos[li * E_ + e];
  int p = atomicAdd(&cursor[li * U_ + u], 1);
  ssrc[(size_t)li * EPL_ + p] = src[li * E_ + e];
}

__global__ __launch_bounds__(256) void pad_fill_k(
    const int* __restrict__ cursor, const int* __restrict__ offs,
    int* __restrict__ ssrc) {
  int t = blockIdx.x * 256 + threadIdx.x;
  if (t >= L_ * U_) return;
  int li = t / U_, u = t % U_;
  int end = cursor[li * U_ + u];
  int pend = offs[li * (U_ + 1) + u + 1];
  int* sp = ssrc + (size_t)li * EPL_;
  for (int p = end; p < pend; ++p) sp[p] = N_;
  if (u == U_ - 1) {
    int ptot = offs[li * (U_ + 1) + U_];
    for (int p = ptot; p < ptot + 8; ++p) sp[p] = N_;
  }
}

// Parity precompute: isdst[li][s] -> P[li][s] (running XOR over layers).
__global__ __launch_bounds__(256) void mark_k(
    const int* __restrict__ dst_unique, char* __restrict__ isdst) {
  int t = blockIdx.x * 256 + threadIdx.x;
  if (t >= L_ * U_) return;
  int li = t / U_;
  isdst[(size_t)li * NP1 + dst_unique[t]] = 1;
}

__global__ __launch_bounds__(256) void ptab_k(
    const char* __restrict__ isdst, char* __restrict__ P) {
  int s = blockIdx.x * 256 + threadIdx.x;
  if (s >= NP1) return;
  char p = 0;
#pragma unroll
  for (int li = 0; li < L_; ++li) {
    P[(size_t)li * NP1 + s] = p;
    p ^= isdst[(size_t)li * NP1 + s];
  }
  P[(size_t)L_ * NP1 + s] = p;
}

__global__ __launch_bounds__(256) void xform_k(
    const int* __restrict__ offs, const char* __restrict__ P,
    int* __restrict__ ssrc) {
  int e = blockIdx.x * 256 + threadIdx.x;
  int li = blockIdx.y;
  if (e >= EPL_) return;
  int ptot = offs[li * (U_ + 1) + U_];
  if (e >= ptot + 8) return;
  int* sp = ssrc + (size_t)li * EPL_;
  int s = sp[e];
  sp[e] = s + NP1 * (int)P[(size_t)li * NP1 + s];
}

__global__ __launch_bounds__(256) void wdst_k(
    const int* __restrict__ dst_unique, const char* __restrict__ P,
    int* __restrict__ wdst) {
  int t = blockIdx.x * 256 + threadIdx.x;
  if (t >= L_ * U_) return;
  int li = t / U_;
  int d = dst_unique[t];
  wdst[t] = d + NP1 * (int)(P[(size_t)li * NP1 + d] ^ 1);
}

// ---------------- Compute ----------------

template <int BC>
__global__ __launch_bounds__(256) void gene_init_k(
    const float* __restrict__ X, const float* __restrict__ w_in,
    const float* __restrict__ b_in, const int* __restrict__ gene_map,
    float4* __restrict__ h4, int c) {
  constexpr int F = BC * 2;
  int t = blockIdx.x * 256 + threadIdx.x;
  if (t >= G_ * BC) return;
  int b = t % BC;
  int g = t / BC;
  float x = X[(c * BC + b) * G_ + g];
  int node = gene_map[g];  // buffer 0 (parity 0 at layer 0)
  float4 out[2];
  __half2* oh = reinterpret_cast<__half2*>(out);
#pragma unroll
  for (int k = 0; k < 8; ++k) {
    float r0 = fmaf(x, w_in[2 * k], b_in[2 * k]);
    float r1 = fmaf(x, w_in[2 * k + 1], b_in[2 * k + 1]);
    oh[k] = __float22half2_rn(make_float2(r0, r1));
  }
  h4[(size_t)node * F + b * 2] = out[0];
  h4[(size_t)node * F + b * 2 + 1] = out[1];
}

// Two-phase fused kernel.
// Phase 1: round-6 gather loop (ping-pong pipeline), flush = packed sums -> LDS.
// Phase 2 (after barrier): dense @W + bias + tanh over the block's 16 u's,
// writing straight into the parity-selected h buffer.
template <int BC>
__global__ __launch_bounds__(256) void gather_fused_k(
    const float4* __restrict__ h4, float4* __restrict__ hw,
    const int* __restrict__ offs, const int* __restrict__ ssrc,
    const float* __restrict__ W, const float* __restrict__ bias,
    const int* __restrict__ dst_unique, const int* __restrict__ wdst, int li) {
  constexpr int F = BC * 2;
  constexpr int RPL = F / 64;
  __shared__ float Wlds[256];
  __shared__ float4 Slds[16][F];  // 16 u's x 2KB sums
  int tid = threadIdx.x;
  Wlds[tid] = W[li * 256 + tid];
  int wave = tid >> 6, lane = tid & 63;
  int w = blockIdx.x * 4 + wave;
  int u0 = w * 4;
  const int* ob = offs + li * (U_ + 1) + u0;
  int offv[5];
#pragma unroll
  for (int i = 0; i < 5; ++i) offv[i] = ob[i];
  const int* sp = ssrc + (size_t)li * EPL_;

  __half2 acc[4][RPL][4];
  const __half2 z = __half2half2(__float2half(0.f));
#pragma unroll
  for (int j = 0; j < 4; ++j)
#pragma unroll
    for (int r = 0; r < RPL; ++r)
#pragma unroll
      for (int k = 0; k < 4; ++k) acc[j][r][k] = z;

  // flush u (block-local index ub = wave*4+uj): packed sums -> LDS only.
  auto flushu = [&](int ub) {
#pragma unroll
    for (int r = 0; r < RPL; ++r) {
      float4 outv;
      __half2* ov = reinterpret_cast<__half2*>(&outv);
#pragma unroll
      for (int k = 0; k < 4; ++k) {
        float2 f0 = __half22float2(acc[0][r][k]);
        float2 f1 = __half22float2(acc[1][r][k]);
        float2 f2 = __half22float2(acc[2][r][k]);
        float2 f3 = __half22float2(acc[3][r][k]);
        ov[k] = __float22half2_rn(make_float2((f0.x + f1.x) + (f2.x + f3.x),
                                              (f0.y + f1.y) + (f2.y + f3.y)));
      }
      Slds[wave * 4 + ub][lane + r * 64] = outv;
    }
#pragma unroll
    for (int j = 0; j < 4; ++j)
#pragma unroll
      for (int r = 0; r < RPL; ++r)
#pragma unroll
        for (int k = 0; k < 4; ++k) acc[j][r][k] = z;
  };

  auto loadRows = [&](float4 (&v)[4][RPL], int4 id) {
    const int* ip = &id.x;
#pragma unroll
    for (int j = 0; j < 4; ++j)
#pragma unroll
      for (int r = 0; r < RPL; ++r)
        v[j][r] = h4[(size_t)ip[j] * F + lane + r * 64];
  };
  auto accum = [&](const float4 (&v)[4][RPL]) {
#pragma unroll
    for (int j = 0; j < 4; ++j)
#pragma unroll
      for (int r = 0; r < RPL; ++r) {
        const __half2* p = reinterpret_cast<const __half2*>(&v[j][r]);
#pragma unroll
        for (int k = 0; k < 4; ++k) acc[j][r][k] = __hadd2(acc[j][r][k], p[k]);
      }
  };

  int e = offv[0];
  int eend = offv[4];
  int uj = 0;
  while (uj < 4 && offv[uj + 1] == e) { flushu(uj); ++uj; }

  if (e < eend) {
    float4 va[4][RPL], vb[4][RPL];
    int4 idC = *(const int4*)(sp + e);
    int4 idN = *(const int4*)(sp + e + 4);  // sentinel tail keeps this in-bounds
    loadRows(va, idC);
    for (;;) {
      loadRows(vb, idN);
      idN = *(const int4*)(sp + e + 8);
      accum(va);
      e += 4;
      if (e == offv[uj + 1]) {
        flushu(uj); ++uj;
        while (uj < 4 && offv[uj + 1] == e) { flushu(uj); ++uj; }
      }
      if (e >= eend) break;
      loadRows(va, idN);
      idN = *(const int4*)(sp + e + 8);
      accum(vb);
      e += 4;
      if (e == offv[uj + 1]) {
        flushu(uj); ++uj;
        while (uj < 4 && offv[uj + 1] == e) { flushu(uj); ++uj; }
      }
      if (e >= eend) break;
    }
  }
  __syncthreads();

  // ---- Phase 2: dense epilogue over the block's 16 u's (static indexing) ----
  int u_blk = blockIdx.x * 16;
#pragma unroll
  for (int it = 0; it < 16 * 64 / 256; ++it) {
    int idx = it * 256 + tid;
    int ul = idx >> 6, b = idx & 63;
    int u = u_blk + ul;
    float4 c0 = Slds[ul][b * 2];
    float4 c1 = Slds[ul][b * 2 + 1];
    float a[16];
    {
      const __half2* p0 = reinterpret_cast<const __half2*>(&c0);
      const __half2* p1 = reinterpret_cast<const __half2*>(&c1);
#pragma unroll
      for (int k = 0; k < 4; ++k) {
        float2 f0 = __half22float2(p0[k]);
        float2 f1 = __half22float2(p1[k]);
        a[2 * k] = f0.x; a[2 * k + 1] = f0.y;
        a[8 + 2 * k] = f1.x; a[8 + 2 * k + 1] = f1.y;
      }
    }
    float m[16];
#pragma unroll
    for (int j = 0; j < 16; ++j) m[j] = 0.f;
#pragma unroll
    for (int d = 0; d < 16; ++d) {
      float s = a[d];
      const float4* wr = (const float4*)&Wlds[d * 16];  // broadcast (free)
      float4 w0 = wr[0], w1 = wr[1], w2 = wr[2], w3 = wr[3];
      m[0] = fmaf(s, w0.x, m[0]);  m[1] = fmaf(s, w0.y, m[1]);
      m[2] = fmaf(s, w0.z, m[2]);  m[3] = fmaf(s, w0.w, m[3]);
      m[4] = fmaf(s, w1.x, m[4]);  m[5] = fmaf(s, w1.y, m[5]);
      m[6] = fmaf(s, w1.z, m[6]);  m[7] = fmaf(s, w1.w, m[7]);
      m[8] = fmaf(s, w2.x, m[8]);  m[9] = fmaf(s, w2.y, m[9]);
      m[10] = fmaf(s, w2.z, m[10]); m[11] = fmaf(s, w2.w, m[11]);
      m[12] = fmaf(s, w3.x, m[12]); m[13] = fmaf(s, w3.y, m[13]);
      m[14] = fmaf(s, w3.z, m[14]); m[15] = fmaf(s, w3.w, m[15]);
    }
    int node = dst_unique[li * U_ + u];  // wave-uniform
    int wrow = wdst[li * U_ + u];
    const float4* bp = (const float4*)(bias + (size_t)node * 16);
    float4 b0 = bp[0], b1 = bp[1], b2 = bp[2], b3 = bp[3];
    float bb[16] = {b0.x, b0.y, b0.z, b0.w, b1.x, b1.y, b1.z, b1.w,
                    b2.x, b2.y, b2.z, b2.w, b3.x, b3.y, b3.z, b3.w};
    float4 o0, o1;
    __half2* ov0 = reinterpret_cast<__half2*>(&o0);
    __half2* ov1 = reinterpret_cast<__half2*>(&o1);
#pragma unroll
    for (int k = 0; k < 4; ++k) {
      ov0[k] = __float22half2_rn(make_float2(tanh_fast(m[2 * k] + bb[2 * k]),
                                             tanh_fast(m[2 * k + 1] + bb[2 * k + 1])));
      ov1[k] = __float22half2_rn(make_float2(tanh_fast(m[8 + 2 * k] + bb[8 + 2 * k]),
                                             tanh_fast(m[8 + 2 * k + 1] + bb[8 + 2 * k + 1])));
    }
    hw[(size_t)wrow * F + b * 2] = o0;
    hw[(size_t)wrow * F + b * 2 + 1] = o1;
  }
}

template <int BC>
__global__ __launch_bounds__(64) void head_k(
    const float4* __restrict__ h4, const float* __restrict__ W_head,
    const float* __restrict__ b_head, const int* __restrict__ root_ids,
    const char* __restrict__ Pfin, float* __restrict__ out, int c) {
  constexpr int F = BC * 2;
  int bl = blockIdx.x;
  int r = threadIdx.x;
  int node = root_ids[r];
  size_t row = (size_t)node + (size_t)NP1 * Pfin[node];
  float4 p0 = h4[row * F + bl * 2];
  float4 p1 = h4[row * F + bl * 2 + 1];
  float v[16];
  const __half2* ph0 = reinterpret_cast<const __half2*>(&p0);
  const __half2* ph1 = reinterpret_cast<const __half2*>(&p1);
#pragma unroll
  for (int k = 0; k < 4; ++k) {
    float2 f0 = __half22float2(ph0[k]);
    float2 f1 = __half22float2(ph1[k]);
    v[2 * k] = f0.x; v[2 * k + 1] = f0.y;
    v[8 + 2 * k] = f1.x; v[8 + 2 * k + 1] = f1.y;
  }
  float acc0 = 0.f, acc1 = 0.f;
#pragma unroll
  for (int d = 0; d < 16; ++d) {
    acc0 = fmaf(v[d], W_head[r * 16 + d], acc0);
    acc1 = fmaf(v[d], W_head[1024 + r * 16 + d], acc1);
  }
  for (int off = 32; off; off >>= 1) {
    acc0 += __shfl_down(acc0, off, 64);
    acc1 += __shfl_down(acc1, off, 64);
  }
  if (r == 0) {
    out[(c * BC + bl) * 2 + 0] = acc0 + b_head[0];
    out[(c * BC + bl) * 2 + 1] = acc1 + b_head[1];
  }
}

__global__ void zero_out_k(float* out, int n) {
  int t = blockIdx.x * 256 + threadIdx.x;
  if (t < n) out[t] = 0.f;
}

// ---------------- Host side ----------------

static size_t need_bytes(int BC) {
  size_t h = (size_t)2 * NP1 * (BC * 2) * 16;           // two h buffers
  size_t csr = (size_t)L_ * U_ * 4 * 3 +                // cnt, cursor, wdst
               (size_t)L_ * (U_ + 1) * 4 +              // offs
               (size_t)L_ * EPL_ * 4 +                  // ssrc
               (size_t)L_ * NP1 +                       // isdst
               (size_t)(L_ + 1) * NP1 + 256;            // P + slack
  return h + csr;
}

template <int BC>
static void run_all(void* const* d_in, void* d_out, void* d_ws, hipStream_t stream) {
  const float* X = (const float*)d_in[0];
  const float* w_in = (const float*)d_in[1];
  const float* b_in = (const float*)d_in[2];
  const float* W = (const float*)d_in[3];
  const float* bias = (const float*)d_in[4];
  const float* W_head = (const float*)d_in[5];
  const float* b_head = (const float*)d_in[6];
  const int* gene_map = (const int*)d_in[7];
  const int* src = (const int*)d_in[8];
  const int* dst_pos = (const int*)d_in[9];
  const int* dst_unique = (const int*)d_in[10];
  const int* root_ids = (const int*)d_in[11];
  float* out = (float*)d_out;

  constexpr int F = BC * 2;
  const size_t hbuf_bytes = (size_t)NP1 * F * 16;  // one buffer
  char* ws = (char*)d_ws;
  float4* h4 = (float4*)ws;                        // [2][NP1][F]
  char* p = ws + 2 * hbuf_bytes;
  int* cnt = (int*)p;      p += (size_t)L_ * U_ * 4;
  int* cursor = (int*)p;   p += (size_t)L_ * U_ * 4;
  int* wdst = (int*)p;     p += (size_t)L_ * U_ * 4;
  int* offs = (int*)p;     p += (size_t)L_ * (U_ + 1) * 4;
  int* ssrc = (int*)p;     p += (size_t)L_ * EPL_ * 4;
  char* isdst = (char*)p;  p += (size_t)L_ * NP1;
  char* P = (char*)p;

  // CSR + parity build (once, batch-independent)
  hipMemsetAsync(cnt, 0, (size_t)L_ * U_ * 4, stream);
  hipMemsetAsync(isdst, 0, (size_t)L_ * NP1, stream);
  dim3 egrid((E_ + 255) / 256, L_);
  hist_kernel<<<egrid, 256, 0, stream>>>(dst_pos, cnt);
  scan_kernel<<<L_, 1024, 0, stream>>>(cnt, offs, cursor);
  scatter_kernel<<<egrid, 256, 0, stream>>>(dst_pos, src, cursor, ssrc);
  pad_fill_k<<<(L_ * U_ + 255) / 256, 256, 0, stream>>>(cursor, offs, ssrc);
  mark_k<<<(L_ * U_ + 255) / 256, 256, 0, stream>>>(dst_unique, isdst);
  ptab_k<<<(NP1 + 255) / 256, 256, 0, stream>>>(isdst, P);
  dim3 xgrid((EPL_ + 255) / 256, L_);
  xform_k<<<xgrid, 256, 0, stream>>>(offs, P, ssrc);
  wdst_k<<<(L_ * U_ + 255) / 256, 256, 0, stream>>>(dst_unique, P, wdst);

  constexpr int nchunks = B_ / BC;
  const int gather_grid = U_ / 16;  // 4 waves/block, 4 u per wave, 16 u per block
  for (int c = 0; c < nchunks; ++c) {
    hipMemsetAsync(h4, 0, hbuf_bytes, stream);  // buffer 0 only
    gene_init_k<BC><<<(G_ * BC + 255) / 256, 256, 0, stream>>>(
        X, w_in, b_in, gene_map, h4, c);
    for (int li = 0; li < L_; ++li) {
      gather_fused_k<BC><<<gather_grid, 256, 0, stream>>>(
          h4, h4, offs, ssrc, W, bias, dst_unique, wdst, li);
    }
    head_k<BC><<<BC, 64, 0, stream>>>(h4, W_head, b_head, root_ids,
                                      P + (size_t)L_ * NP1, out, c);
  }
}

extern "C" void kernel_launch(void* const* d_in, const int* in_sizes, int n_in,
                              void* d_out, int out_size, void* d_ws, size_t ws_size,
                              hipStream_t stream) {
  if (ws_size >= need_bytes(64)) {
    run_all<64>(d_in, d_out, d_ws, stream);
  } else if (ws_size >= need_bytes(32)) {
    run_all<32>(d_in, d_out, d_ws, stream);
  } else if (ws_size >= need_bytes(16)) {
    run_all<16>(d_in, d_out, d_ws, stream);
  } else {
    zero_out_k<<<(out_size + 255) / 256, 256, 0, stream>>>((float*)d_out, out_size);
  }
}

// Round 9
// 713.446 us; speedup vs baseline: 2.9674x; 2.9674x over previous
//
#include <hip/hip_runtime.h>
#include <hip/hip_fp16.h>
#include <cmath>

// Problem constants
constexpr int B_ = 64, N_ = 50000, L_ = 8, E_ = 100000, U_ = 20000, G_ = 20000, R_ = 64, D_ = 16, C_ = 2;
constexpr int EPL_ = E_ + 3 * U_ + 8;  // padded edge slots per layer (+8 sentinel tail)
constexpr int BC = 64;                 // whole batch in one chunk
constexpr int F = BC * 2;              // float4 chunks per node row (2 KB, fp16)

// h fp16 layout: h[node][b][d], d-contiguous. chunk f = b*2 + dh (dh covers d = dh*8..dh*8+7).
// Node N_ is a reserved all-zero row (padding target).

__device__ __forceinline__ float tanh_fast(float x) {
  float e = __expf(2.0f * x);
  return 1.0f - 2.0f * __builtin_amdgcn_rcpf(e + 1.0f);
}

// ---------------- CSR build (batch-independent, counts padded to mult of 4) --

__global__ __launch_bounds__(256) void hist_kernel(
    const int* __restrict__ dst_pos, int* __restrict__ cnt) {
  int e = blockIdx.x * 256 + threadIdx.x;
  int li = blockIdx.y;
  if (e >= E_) return;
  atomicAdd(&cnt[li * U_ + dst_pos[li * E_ + e]], 1);
}

// Fast scan: each thread owns 20 contiguous counts; one LDS scan of 1024 partials.
__global__ __launch_bounds__(1024) void scan_kernel(
    const int* __restrict__ cnt, int* __restrict__ offs, int* __restrict__ cursor) {
  __shared__ int sums[1024];
  int li = blockIdx.x, t = threadIdx.x;
  int base = t * 20;
  int v[20];
  int s = 0;
#pragma unroll
  for (int i = 0; i < 20; ++i) {
    int idx = base + i;
    int c = (idx < U_) ? cnt[li * U_ + idx] : 0;
    v[i] = s;
    s += (c + 3) & ~3;
  }
  sums[t] = s;
  __syncthreads();
  for (int off = 1; off < 1024; off <<= 1) {
    int o = (t >= off) ? sums[t - off] : 0;
    __syncthreads();
    sums[t] += o;
    __syncthreads();
  }
  int excl = sums[t] - s;
#pragma unroll
  for (int i = 0; i < 20; ++i) {
    int idx = base + i;
    if (idx < U_) {
      offs[li * (U_ + 1) + idx] = excl + v[i];
      cursor[li * U_ + idx] = excl + v[i];
    }
  }
  if (t == 1023) offs[li * (U_ + 1) + U_] = sums[1023];
}

__global__ __launch_bounds__(256) void scatter_kernel(
    const int* __restrict__ dst_pos, const int* __restrict__ src,
    int* __restrict__ cursor, int* __restrict__ ssrc) {
  int e = blockIdx.x * 256 + threadIdx.x;
  int li = blockIdx.y;
  if (e >= E_) return;
  int u = dst_pos[li * E_ + e];
  int p = atomicAdd(&cursor[li * U_ + u], 1);
  ssrc[(size_t)li * EPL_ + p] = src[li * E_ + e];
}

__global__ __launch_bounds__(256) void pad_fill_k(
    const int* __restrict__ cursor, const int* __restrict__ offs,
    int* __restrict__ ssrc) {
  int t = blockIdx.x * 256 + threadIdx.x;
  if (t >= L_ * U_) return;
  int li = t / U_, u = t % U_;
  int end = cursor[li * U_ + u];
  int pend = offs[li * (U_ + 1) + u + 1];
  int* sp = ssrc + (size_t)li * EPL_;
  for (int p = end; p < pend; ++p) sp[p] = N_;
  if (u == U_ - 1) {  // 8-int sentinel tail so 2-deep prefetch never reads junk
    int ptot = offs[li * (U_ + 1) + U_];
    for (int p = ptot; p < ptot + 8; ++p) sp[p] = N_;
  }
}

// ---------------- Compute ----------------

__global__ __launch_bounds__(256) void gene_init_k(
    const float* __restrict__ X, const float* __restrict__ w_in,
    const float* __restrict__ b_in, const int* __restrict__ gene_map,
    float4* __restrict__ h4) {
  int t = blockIdx.x * 256 + threadIdx.x;
  if (t >= G_ * BC) return;
  int b = t % BC;
  int g = t / BC;
  float x = X[b * G_ + g];
  int node = gene_map[g];
  float4 out[2];
  __half2* oh = reinterpret_cast<__half2*>(out);
#pragma unroll
  for (int k = 0; k < 8; ++k) {
    float r0 = fmaf(x, w_in[2 * k], b_in[2 * k]);
    float r1 = fmaf(x, w_in[2 * k + 1], b_in[2 * k + 1]);
    oh[k] = __float22half2_rn(make_float2(r0, r1));
  }
  h4[(size_t)node * F + b * 2] = out[0];
  h4[(size_t)node * F + b * 2 + 1] = out[1];
}

// Pure gather-sum: each wave owns 4 consecutive u's = one contiguous padded
// edge range. Ping-pong row buffers (2-deep pipeline), indices 2 groups ahead.
// Two independent fp16 accumulator sets (register diet vs round 6's four).
__global__ __launch_bounds__(256) void gather_k(
    const float4* __restrict__ h4, const int* __restrict__ offs,
    const int* __restrict__ ssrc, float4* __restrict__ agg4, int li) {
  int tid = threadIdx.x;
  int wave = tid >> 6, lane = tid & 63;
  int w = blockIdx.x * 4 + wave;
  int u0 = w * 4;
  const int* ob = offs + li * (U_ + 1) + u0;
  int offv[5];
#pragma unroll
  for (int i = 0; i < 5; ++i) offv[i] = ob[i];
  const int* sp = ssrc + (size_t)li * EPL_;

  __half2 acc[2][2][4];
  const __half2 z = __half2half2(__float2half(0.f));
#pragma unroll
  for (int j = 0; j < 2; ++j)
#pragma unroll
    for (int r = 0; r < 2; ++r)
#pragma unroll
      for (int k = 0; k < 4; ++k) acc[j][r][k] = z;

  auto flushu = [&](int u) {
#pragma unroll
    for (int r = 0; r < 2; ++r) {
      float4 outv;
      __half2* ov = reinterpret_cast<__half2*>(&outv);
#pragma unroll
      for (int k = 0; k < 4; ++k) {
        float2 f0 = __half22float2(acc[0][r][k]);
        float2 f1 = __half22float2(acc[1][r][k]);
        ov[k] = __float22half2_rn(make_float2(f0.x + f1.x, f0.y + f1.y));
      }
      agg4[(size_t)u * F + lane + r * 64] = outv;
    }
#pragma unroll
    for (int j = 0; j < 2; ++j)
#pragma unroll
      for (int r = 0; r < 2; ++r)
#pragma unroll
        for (int k = 0; k < 4; ++k) acc[j][r][k] = z;
  };

  auto loadRows = [&](float4 (&v)[4][2], int4 id) {
    v[0][0] = h4[(size_t)id.x * F + lane]; v[0][1] = h4[(size_t)id.x * F + lane + 64];
    v[1][0] = h4[(size_t)id.y * F + lane]; v[1][1] = h4[(size_t)id.y * F + lane + 64];
    v[2][0] = h4[(size_t)id.z * F + lane]; v[2][1] = h4[(size_t)id.z * F + lane + 64];
    v[3][0] = h4[(size_t)id.w * F + lane]; v[3][1] = h4[(size_t)id.w * F + lane + 64];
  };
  auto accum = [&](const float4 (&v)[4][2]) {
#pragma unroll
    for (int j = 0; j < 4; ++j)
#pragma unroll
      for (int r = 0; r < 2; ++r) {
        const __half2* p = reinterpret_cast<const __half2*>(&v[j][r]);
#pragma unroll
        for (int k = 0; k < 4; ++k)
          acc[j & 1][r][k] = __hadd2(acc[j & 1][r][k], p[k]);
      }
  };

  int e = offv[0];
  int eend = offv[4];
  int uj = 0;
  while (uj < 4 && offv[uj + 1] == e) { flushu(u0 + uj); ++uj; }
  if (e >= eend) return;

  float4 va[4][2], vb[4][2];
  int4 idC = *(const int4*)(sp + e);      // ids for group e
  int4 idN = *(const int4*)(sp + e + 4);  // ids for group e+4 (sentinel-safe)
  loadRows(va, idC);

  for (;;) {
    loadRows(vb, idN);
    idN = *(const int4*)(sp + e + 8);
    accum(va);
    e += 4;
    if (e == offv[uj + 1]) {
      flushu(u0 + uj); ++uj;
      while (uj < 4 && offv[uj + 1] == e) { flushu(u0 + uj); ++uj; }
    }
    if (e >= eend) break;
    loadRows(va, idN);
    idN = *(const int4*)(sp + e + 8);
    accum(vb);
    e += 4;
    if (e == offv[uj + 1]) {
      flushu(u0 + uj); ++uj;
      while (uj < 4 && offv[uj + 1] == e) { flushu(u0 + uj); ++uj; }
    }
    if (e >= eend) break;
  }
}

// Dense epilogue: one thread per (u,b). All-static indexing (no scratch).
// sums (fp16) -> @W + bias + tanh -> h[dst_unique] (fp16), in place.
__global__ __launch_bounds__(256) void dense_k(
    const float4* __restrict__ agg4, const float* __restrict__ W,
    const float* __restrict__ bias, const int* __restrict__ dst_unique,
    float4* __restrict__ h4, int li) {
  __shared__ float Wlds[256];
  int tid = threadIdx.x;
  Wlds[tid] = W[li * 256 + tid];
  __syncthreads();
  int t = blockIdx.x * 256 + tid;
  int u = t >> 6, b = t & 63;
  float4 c0 = agg4[(size_t)u * F + b * 2];
  float4 c1 = agg4[(size_t)u * F + b * 2 + 1];
  float a[16];
  {
    const __half2* p0 = reinterpret_cast<const __half2*>(&c0);
    const __half2* p1 = reinterpret_cast<const __half2*>(&c1);
#pragma unroll
    for (int k = 0; k < 4; ++k) {
      float2 f0 = __half22float2(p0[k]);
      float2 f1 = __half22float2(p1[k]);
      a[2 * k] = f0.x; a[2 * k + 1] = f0.y;
      a[8 + 2 * k] = f1.x; a[8 + 2 * k + 1] = f1.y;
    }
  }
  float m[16];
#pragma unroll
  for (int j = 0; j < 16; ++j) m[j] = 0.f;
#pragma unroll
  for (int d = 0; d < 16; ++d) {
    float s = a[d];
    const float4* wr = (const float4*)&Wlds[d * 16];  // broadcast reads (free)
    float4 w0 = wr[0], w1 = wr[1], w2 = wr[2], w3 = wr[3];
    m[0] = fmaf(s, w0.x, m[0]);  m[1] = fmaf(s, w0.y, m[1]);
    m[2] = fmaf(s, w0.z, m[2]);  m[3] = fmaf(s, w0.w, m[3]);
    m[4] = fmaf(s, w1.x, m[4]);  m[5] = fmaf(s, w1.y, m[5]);
    m[6] = fmaf(s, w1.z, m[6]);  m[7] = fmaf(s, w1.w, m[7]);
    m[8] = fmaf(s, w2.x, m[8]);  m[9] = fmaf(s, w2.y, m[9]);
    m[10] = fmaf(s, w2.z, m[10]); m[11] = fmaf(s, w2.w, m[11]);
    m[12] = fmaf(s, w3.x, m[12]); m[13] = fmaf(s, w3.y, m[13]);
    m[14] = fmaf(s, w3.z, m[14]); m[15] = fmaf(s, w3.w, m[15]);
  }
  int node = dst_unique[li * U_ + u];  // wave-uniform
  const float4* bp = (const float4*)(bias + (size_t)node * 16);
  float4 b0 = bp[0], b1 = bp[1], b2 = bp[2], b3 = bp[3];
  float bb[16] = {b0.x, b0.y, b0.z, b0.w, b1.x, b1.y, b1.z, b1.w,
                  b2.x, b2.y, b2.z, b2.w, b3.x, b3.y, b3.z, b3.w};
  float4 o0, o1;
  __half2* ov0 = reinterpret_cast<__half2*>(&o0);
  __half2* ov1 = reinterpret_cast<__half2*>(&o1);
#pragma unroll
  for (int k = 0; k < 4; ++k) {
    ov0[k] = __float22half2_rn(make_float2(tanh_fast(m[2 * k] + bb[2 * k]),
                                           tanh_fast(m[2 * k + 1] + bb[2 * k + 1])));
    ov1[k] = __float22half2_rn(make_float2(tanh_fast(m[8 + 2 * k] + bb[8 + 2 * k]),
                                           tanh_fast(m[8 + 2 * k + 1] + bb[8 + 2 * k + 1])));
  }
  h4[(size_t)node * F + b * 2] = o0;
  h4[(size_t)node * F + b * 2 + 1] = o1;
}

__global__ __launch_bounds__(64) void head_k(
    const float4* __restrict__ h4, const float* __restrict__ W_head,
    const float* __restrict__ b_head, const int* __restrict__ root_ids,
    float* __restrict__ out) {
  int bl = blockIdx.x;
  int r = threadIdx.x;
  int node = root_ids[r];
  float4 p0 = h4[(size_t)node * F + bl * 2];
  float4 p1 = h4[(size_t)node * F + bl * 2 + 1];
  float v[16];
  const __half2* ph0 = reinterpret_cast<const __half2*>(&p0);
  const __half2* ph1 = reinterpret_cast<const __half2*>(&p1);
#pragma unroll
  for (int k = 0; k < 4; ++k) {
    float2 f0 = __half22float2(ph0[k]);
    float2 f1 = __half22float2(ph1[k]);
    v[2 * k] = f0.x; v[2 * k + 1] = f0.y;
    v[8 + 2 * k] = f1.x; v[8 + 2 * k + 1] = f1.y;
  }
  float acc0 = 0.f, acc1 = 0.f;
#pragma unroll
  for (int d = 0; d < 16; ++d) {
    acc0 = fmaf(v[d], W_head[r * 16 + d], acc0);
    acc1 = fmaf(v[d], W_head[1024 + r * 16 + d], acc1);
  }
  for (int off = 32; off; off >>= 1) {
    acc0 += __shfl_down(acc0, off, 64);
    acc1 += __shfl_down(acc1, off, 64);
  }
  if (r == 0) {
    out[bl * 2 + 0] = acc0 + b_head[0];
    out[bl * 2 + 1] = acc1 + b_head[1];
  }
}

__global__ void zero_out_k(float* out, int n) {
  int t = blockIdx.x * 256 + threadIdx.x;
  if (t < n) out[t] = 0.f;
}

// ---------------- Host side ----------------

static size_t need_bytes() {
  return (size_t)(N_ + 1) * F * 16 + (size_t)U_ * F * 16 +
         (size_t)L_ * U_ * 4 * 2 + (size_t)L_ * (U_ + 1) * 4 +
         (size_t)L_ * EPL_ * 4;
}

extern "C" void kernel_launch(void* const* d_in, const int* in_sizes, int n_in,
                              void* d_out, int out_size, void* d_ws, size_t ws_size,
                              hipStream_t stream) {
  if (ws_size < need_bytes()) {
    zero_out_k<<<(out_size + 255) / 256, 256, 0, stream>>>((float*)d_out, out_size);
    return;
  }
  const float* X = (const float*)d_in[0];
  const float* w_in = (const float*)d_in[1];
  const float* b_in = (const float*)d_in[2];
  const float* W = (const float*)d_in[3];
  const float* bias = (const float*)d_in[4];
  const float* W_head = (const float*)d_in[5];
  const float* b_head = (const float*)d_in[6];
  const int* gene_map = (const int*)d_in[7];
  const int* src = (const int*)d_in[8];
  const int* dst_pos = (const int*)d_in[9];
  const int* dst_unique = (const int*)d_in[10];
  const int* root_ids = (const int*)d_in[11];
  float* out = (float*)d_out;

  const size_t h_bytes = (size_t)(N_ + 1) * F * 16;   // + zero sentinel row
  const size_t agg_bytes = (size_t)U_ * F * 16;
  const size_t cnt_bytes = (size_t)L_ * U_ * 4;
  const size_t offs_bytes = (size_t)L_ * (U_ + 1) * 4;
  const size_t cur_bytes = (size_t)L_ * U_ * 4;

  char* ws = (char*)d_ws;
  float4* h4 = (float4*)ws;
  float4* agg4 = (float4*)(ws + h_bytes);
  int* cnt = (int*)(ws + h_bytes + agg_bytes);
  int* offs = (int*)(ws + h_bytes + agg_bytes + cnt_bytes);
  int* cursor = (int*)(ws + h_bytes + agg_bytes + cnt_bytes + offs_bytes);
  int* ssrc = (int*)(ws + h_bytes + agg_bytes + cnt_bytes + offs_bytes + cur_bytes);

  hipMemsetAsync(cnt, 0, cnt_bytes, stream);
  hipMemsetAsync(h4, 0, h_bytes, stream);
  dim3 egrid((E_ + 255) / 256, L_);
  hist_kernel<<<egrid, 256, 0, stream>>>(dst_pos, cnt);
  scan_kernel<<<L_, 1024, 0, stream>>>(cnt, offs, cursor);
  scatter_kernel<<<egrid, 256, 0, stream>>>(dst_pos, src, cursor, ssrc);
  pad_fill_k<<<(L_ * U_ + 255) / 256, 256, 0, stream>>>(cursor, offs, ssrc);

  gene_init_k<<<(G_ * BC + 255) / 256, 256, 0, stream>>>(X, w_in, b_in, gene_map, h4);

  const int gather_grid = U_ / 16;  // 4 waves/block, 4 u's per wave
  const int dense_grid = U_ * BC / 256;
  for (int li = 0; li < L_; ++li) {
    gather_k<<<gather_grid, 256, 0, stream>>>(h4, offs, ssrc, agg4, li);
    dense_k<<<dense_grid, 256, 0, stream>>>(agg4, W, bias, dst_unique, h4, li);
  }

  head_k<<<BC, 64, 0, stream>>>(h4, W_head, b_head, root_ids, out);
}

// Round 10
// 669.514 us; speedup vs baseline: 3.1621x; 1.0656x over previous
//
#include <hip/hip_runtime.h>
#include <hip/hip_fp16.h>
#include <cmath>

// Problem constants
constexpr int B_ = 64, N_ = 50000, L_ = 8, E_ = 100000, U_ = 20000, G_ = 20000, R_ = 64, D_ = 16, C_ = 2;
constexpr int EPL_ = E_ + 3 * U_ + 8;  // padded edge slots per layer (+8 sentinel tail)
constexpr int BC = 64;                 // whole batch in one chunk
constexpr int F = BC * 2;              // float4 chunks per node row (2 KB, fp16)

// h fp16 layout: h[node][b][d], d-contiguous. chunk f = b*2 + dh (dh covers d = dh*8..dh*8+7).
// Node N_ is a reserved all-zero row (padding target).

__device__ __forceinline__ float tanh_fast(float x) {
  float e = __expf(2.0f * x);
  return 1.0f - 2.0f * __builtin_amdgcn_rcpf(e + 1.0f);
}

// ---------------- CSR build (batch-independent, counts padded to mult of 4) --

// Histogram; also records each edge's rank among same-(li,u) edges
// (the atomicAdd return value — reused by the atomic-free scatter).
__global__ __launch_bounds__(256) void hist_kernel(
    const int* __restrict__ dst_pos, int* __restrict__ cnt,
    int* __restrict__ rank) {
  int e = blockIdx.x * 256 + threadIdx.x;
  int li = blockIdx.y;
  if (e >= E_) return;
  rank[li * E_ + e] = atomicAdd(&cnt[li * U_ + dst_pos[li * E_ + e]], 1);
}

// Fast scan: each thread owns 20 contiguous counts; one LDS scan of 1024 partials.
__global__ __launch_bounds__(1024) void scan_kernel(
    const int* __restrict__ cnt, int* __restrict__ offs) {
  __shared__ int sums[1024];
  int li = blockIdx.x, t = threadIdx.x;
  int base = t * 20;
  int v[20];
  int s = 0;
#pragma unroll
  for (int i = 0; i < 20; ++i) {
    int idx = base + i;
    int c = (idx < U_) ? cnt[li * U_ + idx] : 0;
    v[i] = s;
    s += (c + 3) & ~3;
  }
  sums[t] = s;
  __syncthreads();
  for (int off = 1; off < 1024; off <<= 1) {
    int o = (t >= off) ? sums[t - off] : 0;
    __syncthreads();
    sums[t] += o;
    __syncthreads();
  }
  int excl = sums[t] - s;
#pragma unroll
  for (int i = 0; i < 20; ++i) {
    int idx = base + i;
    if (idx < U_) offs[li * (U_ + 1) + idx] = excl + v[i];
  }
  if (t == 1023) offs[li * (U_ + 1) + U_] = sums[1023];
}

// Atomic-free scatter: position = offs[u] + precomputed rank.
__global__ __launch_bounds__(256) void scatter_kernel(
    const int* __restrict__ dst_pos, const int* __restrict__ src,
    const int* __restrict__ offs, const int* __restrict__ rank,
    int* __restrict__ ssrc) {
  int e = blockIdx.x * 256 + threadIdx.x;
  int li = blockIdx.y;
  if (e >= E_) return;
  int u = dst_pos[li * E_ + e];
  int p = offs[li * (U_ + 1) + u] + rank[li * E_ + e];
  ssrc[(size_t)li * EPL_ + p] = src[li * E_ + e];
}

__global__ __launch_bounds__(256) void pad_fill_k(
    const int* __restrict__ cnt, const int* __restrict__ offs,
    int* __restrict__ ssrc) {
  int t = blockIdx.x * 256 + threadIdx.x;
  if (t >= L_ * U_) return;
  int li = t / U_, u = t % U_;
  int end = offs[li * (U_ + 1) + u] + cnt[li * U_ + u];  // real end
  int pend = offs[li * (U_ + 1) + u + 1];                // padded end
  int* sp = ssrc + (size_t)li * EPL_;
  for (int p = end; p < pend; ++p) sp[p] = N_;
  if (u == U_ - 1) {  // 8-int sentinel tail so 2-deep prefetch never reads junk
    int ptot = offs[li * (U_ + 1) + U_];
    for (int p = ptot; p < ptot + 8; ++p) sp[p] = N_;
  }
}

// ---------------- Compute ----------------

__global__ __launch_bounds__(256) void gene_init_k(
    const float* __restrict__ X, const float* __restrict__ w_in,
    const float* __restrict__ b_in, const int* __restrict__ gene_map,
    float4* __restrict__ h4) {
  int t = blockIdx.x * 256 + threadIdx.x;
  if (t >= G_ * BC) return;
  int b = t % BC;
  int g = t / BC;
  float x = X[b * G_ + g];
  int node = gene_map[g];
  float4 out[2];
  __half2* oh = reinterpret_cast<__half2*>(out);
#pragma unroll
  for (int k = 0; k < 8; ++k) {
    float r0 = fmaf(x, w_in[2 * k], b_in[2 * k]);
    float r1 = fmaf(x, w_in[2 * k + 1], b_in[2 * k + 1]);
    oh[k] = __float22half2_rn(make_float2(r0, r1));
  }
  h4[(size_t)node * F + b * 2] = out[0];
  h4[(size_t)node * F + b * 2 + 1] = out[1];
}

// Pure gather-sum: each wave owns 4 consecutive u's = one contiguous padded
// edge range. Ping-pong row buffers (2-deep pipeline), indices 2 groups ahead.
// Two independent fp16 accumulator sets.
__global__ __launch_bounds__(256) void gather_k(
    const float4* __restrict__ h4, const int* __restrict__ offs,
    const int* __restrict__ ssrc, float4* __restrict__ agg4, int li) {
  int tid = threadIdx.x;
  int wave = tid >> 6, lane = tid & 63;
  int w = blockIdx.x * 4 + wave;
  int u0 = w * 4;
  const int* ob = offs + li * (U_ + 1) + u0;
  int offv[5];
#pragma unroll
  for (int i = 0; i < 5; ++i) offv[i] = ob[i];
  const int* sp = ssrc + (size_t)li * EPL_;

  __half2 acc[2][2][4];
  const __half2 z = __half2half2(__float2half(0.f));
#pragma unroll
  for (int j = 0; j < 2; ++j)
#pragma unroll
    for (int r = 0; r < 2; ++r)
#pragma unroll
      for (int k = 0; k < 4; ++k) acc[j][r][k] = z;

  auto flushu = [&](int u) {
#pragma unroll
    for (int r = 0; r < 2; ++r) {
      float4 outv;
      __half2* ov = reinterpret_cast<__half2*>(&outv);
#pragma unroll
      for (int k = 0; k < 4; ++k) {
        float2 f0 = __half22float2(acc[0][r][k]);
        float2 f1 = __half22float2(acc[1][r][k]);
        ov[k] = __float22half2_rn(make_float2(f0.x + f1.x, f0.y + f1.y));
      }
      agg4[(size_t)u * F + lane + r * 64] = outv;
    }
#pragma unroll
    for (int j = 0; j < 2; ++j)
#pragma unroll
      for (int r = 0; r < 2; ++r)
#pragma unroll
        for (int k = 0; k < 4; ++k) acc[j][r][k] = z;
  };

  auto loadRows = [&](float4 (&v)[4][2], int4 id) {
    v[0][0] = h4[(size_t)id.x * F + lane]; v[0][1] = h4[(size_t)id.x * F + lane + 64];
    v[1][0] = h4[(size_t)id.y * F + lane]; v[1][1] = h4[(size_t)id.y * F + lane + 64];
    v[2][0] = h4[(size_t)id.z * F + lane]; v[2][1] = h4[(size_t)id.z * F + lane + 64];
    v[3][0] = h4[(size_t)id.w * F + lane]; v[3][1] = h4[(size_t)id.w * F + lane + 64];
  };
  auto accum = [&](const float4 (&v)[4][2]) {
#pragma unroll
    for (int j = 0; j < 4; ++j)
#pragma unroll
      for (int r = 0; r < 2; ++r) {
        const __half2* p = reinterpret_cast<const __half2*>(&v[j][r]);
#pragma unroll
        for (int k = 0; k < 4; ++k)
          acc[j & 1][r][k] = __hadd2(acc[j & 1][r][k], p[k]);
      }
  };

  int e = offv[0];
  int eend = offv[4];
  int uj = 0;
  while (uj < 4 && offv[uj + 1] == e) { flushu(u0 + uj); ++uj; }
  if (e >= eend) return;

  float4 va[4][2], vb[4][2];
  int4 idC = *(const int4*)(sp + e);      // ids for group e
  int4 idN = *(const int4*)(sp + e + 4);  // ids for group e+4 (sentinel-safe)
  loadRows(va, idC);

  for (;;) {
    loadRows(vb, idN);
    idN = *(const int4*)(sp + e + 8);
    accum(va);
    e += 4;
    if (e == offv[uj + 1]) {
      flushu(u0 + uj); ++uj;
      while (uj < 4 && offv[uj + 1] == e) { flushu(u0 + uj); ++uj; }
    }
    if (e >= eend) break;
    loadRows(va, idN);
    idN = *(const int4*)(sp + e + 8);
    accum(vb);
    e += 4;
    if (e == offv[uj + 1]) {
      flushu(u0 + uj); ++uj;
      while (uj < 4 && offv[uj + 1] == e) { flushu(u0 + uj); ++uj; }
    }
    if (e >= eend) break;
  }
}

// Dense epilogue: one thread per (u,b). All-static indexing (no scratch).
// sums (fp16) -> @W + bias + tanh -> h[dst_unique] (fp16), in place.
__global__ __launch_bounds__(256) void dense_k(
    const float4* __restrict__ agg4, const float* __restrict__ W,
    const float* __restrict__ bias, const int* __restrict__ dst_unique,
    float4* __restrict__ h4, int li) {
  __shared__ float Wlds[256];
  int tid = threadIdx.x;
  Wlds[tid] = W[li * 256 + tid];
  __syncthreads();
  int t = blockIdx.x * 256 + tid;
  int u = t >> 6, b = t & 63;
  float4 c0 = agg4[(size_t)u * F + b * 2];
  float4 c1 = agg4[(size_t)u * F + b * 2 + 1];
  float a[16];
  {
    const __half2* p0 = reinterpret_cast<const __half2*>(&c0);
    const __half2* p1 = reinterpret_cast<const __half2*>(&c1);
#pragma unroll
    for (int k = 0; k < 4; ++k) {
      float2 f0 = __half22float2(p0[k]);
      float2 f1 = __half22float2(p1[k]);
      a[2 * k] = f0.x; a[2 * k + 1] = f0.y;
      a[8 + 2 * k] = f1.x; a[8 + 2 * k + 1] = f1.y;
    }
  }
  float m[16];
#pragma unroll
  for (int j = 0; j < 16; ++j) m[j] = 0.f;
#pragma unroll
  for (int d = 0; d < 16; ++d) {
    float s = a[d];
    const float4* wr = (const float4*)&Wlds[d * 16];  // broadcast reads (free)
    float4 w0 = wr[0], w1 = wr[1], w2 = wr[2], w3 = wr[3];
    m[0] = fmaf(s, w0.x, m[0]);  m[1] = fmaf(s, w0.y, m[1]);
    m[2] = fmaf(s, w0.z, m[2]);  m[3] = fmaf(s, w0.w, m[3]);
    m[4] = fmaf(s, w1.x, m[4]);  m[5] = fmaf(s, w1.y, m[5]);
    m[6] = fmaf(s, w1.z, m[6]);  m[7] = fmaf(s, w1.w, m[7]);
    m[8] = fmaf(s, w2.x, m[8]);  m[9] = fmaf(s, w2.y, m[9]);
    m[10] = fmaf(s, w2.z, m[10]); m[11] = fmaf(s, w2.w, m[11]);
    m[12] = fmaf(s, w3.x, m[12]); m[13] = fmaf(s, w3.y, m[13]);
    m[14] = fmaf(s, w3.z, m[14]); m[15] = fmaf(s, w3.w, m[15]);
  }
  int node = dst_unique[li * U_ + u];  // wave-uniform
  const float4* bp = (const float4*)(bias + (size_t)node * 16);
  float4 b0 = bp[0], b1 = bp[1], b2 = bp[2], b3 = bp[3];
  float bb[16] = {b0.x, b0.y, b0.z, b0.w, b1.x, b1.y, b1.z, b1.w,
                  b2.x, b2.y, b2.z, b2.w, b3.x, b3.y, b3.z, b3.w};
  float4 o0, o1;
  __half2* ov0 = reinterpret_cast<__half2*>(&o0);
  __half2* ov1 = reinterpret_cast<__half2*>(&o1);
#pragma unroll
  for (int k = 0; k < 4; ++k) {
    ov0[k] = __float22half2_rn(make_float2(tanh_fast(m[2 * k] + bb[2 * k]),
                                           tanh_fast(m[2 * k + 1] + bb[2 * k + 1])));
    ov1[k] = __float22half2_rn(make_float2(tanh_fast(m[8 + 2 * k] + bb[8 + 2 * k]),
                                           tanh_fast(m[8 + 2 * k + 1] + bb[8 + 2 * k + 1])));
  }
  h4[(size_t)node * F + b * 2] = o0;
  h4[(size_t)node * F + b * 2 + 1] = o1;
}

__global__ __launch_bounds__(64) void head_k(
    const float4* __restrict__ h4, const float* __restrict__ W_head,
    const float* __restrict__ b_head, const int* __restrict__ root_ids,
    float* __restrict__ out) {
  int bl = blockIdx.x;
  int r = threadIdx.x;
  int node = root_ids[r];
  float4 p0 = h4[(size_t)node * F + bl * 2];
  float4 p1 = h4[(size_t)node * F + bl * 2 + 1];
  float v[16];
  const __half2* ph0 = reinterpret_cast<const __half2*>(&p0);
  const __half2* ph1 = reinterpret_cast<const __half2*>(&p1);
#pragma unroll
  for (int k = 0; k < 4; ++k) {
    float2 f0 = __half22float2(ph0[k]);
    float2 f1 = __half22float2(ph1[k]);
    v[2 * k] = f0.x; v[2 * k + 1] = f0.y;
    v[8 + 2 * k] = f1.x; v[8 + 2 * k + 1] = f1.y;
  }
  float acc0 = 0.f, acc1 = 0.f;
#pragma unroll
  for (int d = 0; d < 16; ++d) {
    acc0 = fmaf(v[d], W_head[r * 16 + d], acc0);
    acc1 = fmaf(v[d], W_head[1024 + r * 16 + d], acc1);
  }
  for (int off = 32; off; off >>= 1) {
    acc0 += __shfl_down(acc0, off, 64);
    acc1 += __shfl_down(acc1, off, 64);
  }
  if (r == 0) {
    out[bl * 2 + 0] = acc0 + b_head[0];
    out[bl * 2 + 1] = acc1 + b_head[1];
  }
}

__global__ void zero_out_k(float* out, int n) {
  int t = blockIdx.x * 256 + threadIdx.x;
  if (t < n) out[t] = 0.f;
}

// ---------------- Host side ----------------

static size_t need_bytes() {
  return (size_t)(N_ + 1) * F * 16 + (size_t)U_ * F * 16 +
         (size_t)L_ * U_ * 4 +            // cnt
         (size_t)L_ * (U_ + 1) * 4 +      // offs
         (size_t)L_ * E_ * 4 +            // rank
         (size_t)L_ * EPL_ * 4;           // ssrc
}

extern "C" void kernel_launch(void* const* d_in, const int* in_sizes, int n_in,
                              void* d_out, int out_size, void* d_ws, size_t ws_size,
                              hipStream_t stream) {
  if (ws_size < need_bytes()) {
    zero_out_k<<<(out_size + 255) / 256, 256, 0, stream>>>((float*)d_out, out_size);
    return;
  }
  const float* X = (const float*)d_in[0];
  const float* w_in = (const float*)d_in[1];
  const float* b_in = (const float*)d_in[2];
  const float* W = (const float*)d_in[3];
  const float* bias = (const float*)d_in[4];
  const float* W_head = (const float*)d_in[5];
  const float* b_head = (const float*)d_in[6];
  const int* gene_map = (const int*)d_in[7];
  const int* src = (const int*)d_in[8];
  const int* dst_pos = (const int*)d_in[9];
  const int* dst_unique = (const int*)d_in[10];
  const int* root_ids = (const int*)d_in[11];
  float* out = (float*)d_out;

  const size_t h_bytes = (size_t)(N_ + 1) * F * 16;   // + zero sentinel row
  const size_t agg_bytes = (size_t)U_ * F * 16;
  const size_t cnt_bytes = (size_t)L_ * U_ * 4;
  const size_t offs_bytes = (size_t)L_ * (U_ + 1) * 4;
  const size_t rank_bytes = (size_t)L_ * E_ * 4;

  char* ws = (char*)d_ws;
  float4* h4 = (float4*)ws;
  float4* agg4 = (float4*)(ws + h_bytes);
  int* cnt = (int*)(ws + h_bytes + agg_bytes);
  int* offs = (int*)(ws + h_bytes + agg_bytes + cnt_bytes);
  int* rank = (int*)(ws + h_bytes + agg_bytes + cnt_bytes + offs_bytes);
  int* ssrc = (int*)(ws + h_bytes + agg_bytes + cnt_bytes + offs_bytes + rank_bytes);

  hipMemsetAsync(cnt, 0, cnt_bytes, stream);
  hipMemsetAsync(h4, 0, h_bytes, stream);
  dim3 egrid((E_ + 255) / 256, L_);
  hist_kernel<<<egrid, 256, 0, stream>>>(dst_pos, cnt, rank);
  scan_kernel<<<L_, 1024, 0, stream>>>(cnt, offs);
  scatter_kernel<<<egrid, 256, 0, stream>>>(dst_pos, src, offs, rank, ssrc);
  pad_fill_k<<<(L_ * U_ + 255) / 256, 256, 0, stream>>>(cnt, offs, ssrc);

  gene_init_k<<<(G_ * BC + 255) / 256, 256, 0, stream>>>(X, w_in, b_in, gene_map, h4);

  const int gather_grid = U_ / 16;  // 4 waves/block, 4 u's per wave
  const int dense_grid = U_ * BC / 256;
  for (int li = 0; li < L_; ++li) {
    gather_k<<<gather_grid, 256, 0, stream>>>(h4, offs, ssrc, agg4, li);
    dense_k<<<dense_grid, 256, 0, stream>>>(agg4, W, bias, dst_unique, h4, li);
  }

  head_k<<<BC, 64, 0, stream>>>(h4, W_head, b_head, root_ids, out);
}

// Round 11
// 626.879 us; speedup vs baseline: 3.3772x; 1.0680x over previous
//
#include <hip/hip_runtime.h>
#include <hip/hip_fp16.h>
#include <cmath>

// Problem constants
constexpr int B_ = 64, N_ = 50000, L_ = 8, E_ = 100000, U_ = 20000, G_ = 20000, R_ = 64, D_ = 16, C_ = 2;
constexpr int EPL_ = E_ + 3 * U_ + 4096;  // padded edge slots per layer (+slack for empty-u forced pad)
constexpr int EPLG_ = EPL_ / 4 + 16;      // group slots per layer (ug table)
constexpr int GPW = 8;                    // groups per wave (32 edges) — balanced spans
constexpr int BC = 64;                    // whole batch in one chunk
constexpr int F = BC * 2;                 // float4 chunks per node row (2 KB, fp16)

// h fp16 layout: h[node][b][d], d-contiguous. chunk f = b*2 + dh.
// Node N_ is a reserved all-zero row (padding target).
// ug[g] = u owning edge-group g (groups never straddle u's); -1 past the end.

__device__ __forceinline__ float tanh_fast(float x) {
  float e = __expf(2.0f * x);
  return 1.0f - 2.0f * __builtin_amdgcn_rcpf(e + 1.0f);
}

// ---------------- CSR build (batch-independent) ----------------

// Histogram; also records each edge's rank among same-(li,u) edges.
__global__ __launch_bounds__(256) void hist_kernel(
    const int* __restrict__ dst_pos, int* __restrict__ cnt,
    int* __restrict__ rank) {
  int e = blockIdx.x * 256 + threadIdx.x;
  int li = blockIdx.y;
  if (e >= E_) return;
  rank[li * E_ + e] = atomicAdd(&cnt[li * U_ + dst_pos[li * E_ + e]], 1);
}

// Fast scan; counts padded to mult of 4, empty u's forced to 4 slots
// (so every u appears in ug and gets flushed with zero sums).
__global__ __launch_bounds__(1024) void scan_kernel(
    const int* __restrict__ cnt, int* __restrict__ offs) {
  __shared__ int sums[1024];
  int li = blockIdx.x, t = threadIdx.x;
  int base = t * 20;
  int v[20];
  int s = 0;
#pragma unroll
  for (int i = 0; i < 20; ++i) {
    int idx = base + i;
    int c = (idx < U_) ? cnt[li * U_ + idx] : -1;
    int pc = (c < 0) ? 0 : ((c == 0) ? 4 : ((c + 3) & ~3));
    v[i] = s;
    s += pc;
  }
  sums[t] = s;
  __syncthreads();
  for (int off = 1; off < 1024; off <<= 1) {
    int o = (t >= off) ? sums[t - off] : 0;
    __syncthreads();
    sums[t] += o;
    __syncthreads();
  }
  int excl = sums[t] - s;
#pragma unroll
  for (int i = 0; i < 20; ++i) {
    int idx = base + i;
    if (idx < U_) offs[li * (U_ + 1) + idx] = excl + v[i];
  }
  if (t == 1023) offs[li * (U_ + 1) + U_] = sums[1023];
}

// Atomic-free scatter: position = offs[u] + precomputed rank.
__global__ __launch_bounds__(256) void scatter_kernel(
    const int* __restrict__ dst_pos, const int* __restrict__ src,
    const int* __restrict__ offs, const int* __restrict__ rank,
    int* __restrict__ ssrc) {
  int e = blockIdx.x * 256 + threadIdx.x;
  int li = blockIdx.y;
  if (e >= E_) return;
  int u = dst_pos[li * E_ + e];
  int p = offs[li * (U_ + 1) + u] + rank[li * E_ + e];
  ssrc[(size_t)li * EPL_ + p] = src[li * E_ + e];
}

// Pad sentinel edges + build ug (group -> u) table. ug pre-memset to -1.
__global__ __launch_bounds__(256) void pad_fill_ug_k(
    const int* __restrict__ cnt, const int* __restrict__ offs,
    int* __restrict__ ssrc, int* __restrict__ ug) {
  int t = blockIdx.x * 256 + threadIdx.x;
  if (t >= L_ * U_) return;
  int li = t / U_, u = t % U_;
  int start = offs[li * (U_ + 1) + u];
  int end = start + cnt[li * U_ + u];       // real end
  int pend = offs[li * (U_ + 1) + u + 1];   // padded end
  int* sp = ssrc + (size_t)li * EPL_;
  for (int p = end; p < pend; ++p) sp[p] = N_;
  int* ugp = ug + (size_t)li * EPLG_;
  for (int g = start >> 2; g < (pend >> 2); ++g) ugp[g] = u;
  if (u == U_ - 1) {  // 8-int sentinel tail so prefetch never reads junk
    int ptot = offs[li * (U_ + 1) + U_];
    for (int p = ptot; p < ptot + 8; ++p) sp[p] = N_;
  }
}

// ---------------- Compute ----------------

__global__ __launch_bounds__(256) void gene_init_k(
    const float* __restrict__ X, const float* __restrict__ w_in,
    const float* __restrict__ b_in, const int* __restrict__ gene_map,
    float4* __restrict__ h4) {
  int t = blockIdx.x * 256 + threadIdx.x;
  if (t >= G_ * BC) return;
  int b = t % BC;
  int g = t / BC;
  float x = X[b * G_ + g];
  int node = gene_map[g];
  float4 out[2];
  __half2* oh = reinterpret_cast<__half2*>(out);
#pragma unroll
  for (int k = 0; k < 8; ++k) {
    float r0 = fmaf(x, w_in[2 * k], b_in[2 * k]);
    float r1 = fmaf(x, w_in[2 * k + 1], b_in[2 * k + 1]);
    oh[k] = __float22half2_rn(make_float2(r0, r1));
  }
  h4[(size_t)node * F + b * 2] = out[0];
  h4[(size_t)node * F + b * 2 + 1] = out[1];
}

// Balanced gather-sum: each wave owns GPW consecutive edge-groups. It skips
// the tail of a u begun in the previous span, then processes every u that
// STARTS in its span to completion (running past the span end if needed).
// 2-deep ping-pong row pipeline; fp16 packed accumulation.
__global__ __launch_bounds__(256) void gather_k(
    const float4* __restrict__ h4, const int* __restrict__ ug,
    const int* __restrict__ ssrc, float4* __restrict__ agg4, int li) {
  int tid = threadIdx.x;
  int wave = tid >> 6, lane = tid & 63;
  int wv = blockIdx.x * 4 + wave;
  int g0 = wv * GPW, gend = g0 + GPW;
  const int* ugp = ug + (size_t)li * EPLG_;
  const int* sp = ssrc + (size_t)li * EPL_;

  // prologue: skip tail of the u begun by the previous span
  int prevU = (g0 == 0) ? -2 : ugp[g0 - 1];
  int g = g0;
  while (g < gend && ugp[g] == prevU) ++g;
  if (g >= gend) return;
  int curU = ugp[g];
  if (curU < 0) return;

  __half2 acc[2][2][4];
  const __half2 z = __half2half2(__float2half(0.f));
#pragma unroll
  for (int j = 0; j < 2; ++j)
#pragma unroll
    for (int r = 0; r < 2; ++r)
#pragma unroll
      for (int k = 0; k < 4; ++k) acc[j][r][k] = z;

  auto flushu = [&](int u) {
#pragma unroll
    for (int r = 0; r < 2; ++r) {
      float4 outv;
      __half2* ov = reinterpret_cast<__half2*>(&outv);
#pragma unroll
      for (int k = 0; k < 4; ++k) {
        float2 f0 = __half22float2(acc[0][r][k]);
        float2 f1 = __half22float2(acc[1][r][k]);
        ov[k] = __float22half2_rn(make_float2(f0.x + f1.x, f0.y + f1.y));
      }
      agg4[(size_t)u * F + lane + r * 64] = outv;
    }
#pragma unroll
    for (int j = 0; j < 2; ++j)
#pragma unroll
      for (int r = 0; r < 2; ++r)
#pragma unroll
        for (int k = 0; k < 4; ++k) acc[j][r][k] = z;
  };

  auto loadRows = [&](float4 (&v)[4][2], int4 id) {
    v[0][0] = h4[(size_t)id.x * F + lane]; v[0][1] = h4[(size_t)id.x * F + lane + 64];
    v[1][0] = h4[(size_t)id.y * F + lane]; v[1][1] = h4[(size_t)id.y * F + lane + 64];
    v[2][0] = h4[(size_t)id.z * F + lane]; v[2][1] = h4[(size_t)id.z * F + lane + 64];
    v[3][0] = h4[(size_t)id.w * F + lane]; v[3][1] = h4[(size_t)id.w * F + lane + 64];
  };
  auto accum = [&](const float4 (&v)[4][2]) {
#pragma unroll
    for (int j = 0; j < 4; ++j)
#pragma unroll
      for (int r = 0; r < 2; ++r) {
        const __half2* p = reinterpret_cast<const __half2*>(&v[j][r]);
#pragma unroll
        for (int k = 0; k < 4; ++k)
          acc[j & 1][r][k] = __hadd2(acc[j & 1][r][k], p[k]);
      }
  };

  float4 va[4][2], vb[4][2];
  int4 idA = *(const int4*)(sp + 4 * g);
  loadRows(va, idA);
  int nuA = ugp[g + 1];
  int nuB;

  for (;;) {
    // phase A: current group in va
    {
      bool more = (nuA >= 0) && ((nuA == curU) || (g + 1 < gend));
      if (more) {
        int4 idB = *(const int4*)(sp + 4 * (g + 1));
        loadRows(vb, idB);
        nuB = ugp[g + 2];
      }
      accum(va);
      if (nuA != curU) {
        flushu(curU);
        if (!more) return;
        curU = nuA;
      }
      ++g;
    }
    // phase B: current group in vb
    {
      bool more = (nuB >= 0) && ((nuB == curU) || (g + 1 < gend));
      if (more) {
        int4 idA2 = *(const int4*)(sp + 4 * (g + 1));
        loadRows(va, idA2);
        nuA = ugp[g + 2];
      }
      accum(vb);
      if (nuB != curU) {
        flushu(curU);
        if (!more) return;
        curU = nuB;
      }
      ++g;
    }
  }
}

// Dense epilogue: one thread per (u,b). All-static indexing (no scratch).
__global__ __launch_bounds__(256) void dense_k(
    const float4* __restrict__ agg4, const float* __restrict__ W,
    const float* __restrict__ bias, const int* __restrict__ dst_unique,
    float4* __restrict__ h4, int li) {
  __shared__ float Wlds[256];
  int tid = threadIdx.x;
  Wlds[tid] = W[li * 256 + tid];
  __syncthreads();
  int t = blockIdx.x * 256 + tid;
  int u = t >> 6, b = t & 63;
  float4 c0 = agg4[(size_t)u * F + b * 2];
  float4 c1 = agg4[(size_t)u * F + b * 2 + 1];
  float a[16];
  {
    const __half2* p0 = reinterpret_cast<const __half2*>(&c0);
    const __half2* p1 = reinterpret_cast<const __half2*>(&c1);
#pragma unroll
    for (int k = 0; k < 4; ++k) {
      float2 f0 = __half22float2(p0[k]);
      float2 f1 = __half22float2(p1[k]);
      a[2 * k] = f0.x; a[2 * k + 1] = f0.y;
      a[8 + 2 * k] = f1.x; a[8 + 2 * k + 1] = f1.y;
    }
  }
  float m[16];
#pragma unroll
  for (int j = 0; j < 16; ++j) m[j] = 0.f;
#pragma unroll
  for (int d = 0; d < 16; ++d) {
    float s = a[d];
    const float4* wr = (const float4*)&Wlds[d * 16];  // broadcast reads (free)
    float4 w0 = wr[0], w1 = wr[1], w2 = wr[2], w3 = wr[3];
    m[0] = fmaf(s, w0.x, m[0]);  m[1] = fmaf(s, w0.y, m[1]);
    m[2] = fmaf(s, w0.z, m[2]);  m[3] = fmaf(s, w0.w, m[3]);
    m[4] = fmaf(s, w1.x, m[4]);  m[5] = fmaf(s, w1.y, m[5]);
    m[6] = fmaf(s, w1.z, m[6]);  m[7] = fmaf(s, w1.w, m[7]);
    m[8] = fmaf(s, w2.x, m[8]);  m[9] = fmaf(s, w2.y, m[9]);
    m[10] = fmaf(s, w2.z, m[10]); m[11] = fmaf(s, w2.w, m[11]);
    m[12] = fmaf(s, w3.x, m[12]); m[13] = fmaf(s, w3.y, m[13]);
    m[14] = fmaf(s, w3.z, m[14]); m[15] = fmaf(s, w3.w, m[15]);
  }
  int node = dst_unique[li * U_ + u];  // wave-uniform
  const float4* bp = (const float4*)(bias + (size_t)node * 16);
  float4 b0 = bp[0], b1 = bp[1], b2 = bp[2], b3 = bp[3];
  float bb[16] = {b0.x, b0.y, b0.z, b0.w, b1.x, b1.y, b1.z, b1.w,
                  b2.x, b2.y, b2.z, b2.w, b3.x, b3.y, b3.z, b3.w};
  float4 o0, o1;
  __half2* ov0 = reinterpret_cast<__half2*>(&o0);
  __half2* ov1 = reinterpret_cast<__half2*>(&o1);
#pragma unroll
  for (int k = 0; k < 4; ++k) {
    ov0[k] = __float22half2_rn(make_float2(tanh_fast(m[2 * k] + bb[2 * k]),
                                           tanh_fast(m[2 * k + 1] + bb[2 * k + 1])));
    ov1[k] = __float22half2_rn(make_float2(tanh_fast(m[8 + 2 * k] + bb[8 + 2 * k]),
                                           tanh_fast(m[8 + 2 * k + 1] + bb[8 + 2 * k + 1])));
  }
  h4[(size_t)node * F + b * 2] = o0;
  h4[(size_t)node * F + b * 2 + 1] = o1;
}

__global__ __launch_bounds__(64) void head_k(
    const float4* __restrict__ h4, const float* __restrict__ W_head,
    const float* __restrict__ b_head, const int* __restrict__ root_ids,
    float* __restrict__ out) {
  int bl = blockIdx.x;
  int r = threadIdx.x;
  int node = root_ids[r];
  float4 p0 = h4[(size_t)node * F + bl * 2];
  float4 p1 = h4[(size_t)node * F + bl * 2 + 1];
  float v[16];
  const __half2* ph0 = reinterpret_cast<const __half2*>(&p0);
  const __half2* ph1 = reinterpret_cast<const __half2*>(&p1);
#pragma unroll
  for (int k = 0; k < 4; ++k) {
    float2 f0 = __half22float2(ph0[k]);
    float2 f1 = __half22float2(ph1[k]);
    v[2 * k] = f0.x; v[2 * k + 1] = f0.y;
    v[8 + 2 * k] = f1.x; v[8 + 2 * k + 1] = f1.y;
  }
  float acc0 = 0.f, acc1 = 0.f;
#pragma unroll
  for (int d = 0; d < 16; ++d) {
    acc0 = fmaf(v[d], W_head[r * 16 + d], acc0);
    acc1 = fmaf(v[d], W_head[1024 + r * 16 + d], acc1);
  }
  for (int off = 32; off; off >>= 1) {
    acc0 += __shfl_down(acc0, off, 64);
    acc1 += __shfl_down(acc1, off, 64);
  }
  if (r == 0) {
    out[bl * 2 + 0] = acc0 + b_head[0];
    out[bl * 2 + 1] = acc1 + b_head[1];
  }
}

__global__ void zero_out_k(float* out, int n) {
  int t = blockIdx.x * 256 + threadIdx.x;
  if (t < n) out[t] = 0.f;
}

// ---------------- Host side ----------------

static size_t need_bytes() {
  return (size_t)(N_ + 1) * F * 16 + (size_t)U_ * F * 16 +
         (size_t)L_ * U_ * 4 +            // cnt
         (size_t)L_ * (U_ + 1) * 4 +      // offs
         (size_t)L_ * E_ * 4 +            // rank (aliased as ug after scatter)
         (size_t)L_ * EPL_ * 4;           // ssrc
}

extern "C" void kernel_launch(void* const* d_in, const int* in_sizes, int n_in,
                              void* d_out, int out_size, void* d_ws, size_t ws_size,
                              hipStream_t stream) {
  if (ws_size < need_bytes()) {
    zero_out_k<<<(out_size + 255) / 256, 256, 0, stream>>>((float*)d_out, out_size);
    return;
  }
  const float* X = (const float*)d_in[0];
  const float* w_in = (const float*)d_in[1];
  const float* b_in = (const float*)d_in[2];
  const float* W = (const float*)d_in[3];
  const float* bias = (const float*)d_in[4];
  const float* W_head = (const float*)d_in[5];
  const float* b_head = (const float*)d_in[6];
  const int* gene_map = (const int*)d_in[7];
  const int* src = (const int*)d_in[8];
  const int* dst_pos = (const int*)d_in[9];
  const int* dst_unique = (const int*)d_in[10];
  const int* root_ids = (const int*)d_in[11];
  float* out = (float*)d_out;

  const size_t h_bytes = (size_t)(N_ + 1) * F * 16;   // + zero sentinel row
  const size_t agg_bytes = (size_t)U_ * F * 16;
  const size_t cnt_bytes = (size_t)L_ * U_ * 4;
  const size_t offs_bytes = (size_t)L_ * (U_ + 1) * 4;
  const size_t rank_bytes = (size_t)L_ * E_ * 4;
  const size_t ug_bytes = (size_t)L_ * EPLG_ * 4;     // 1.31 MB <= rank_bytes

  char* ws = (char*)d_ws;
  float4* h4 = (float4*)ws;
  float4* agg4 = (float4*)(ws + h_bytes);
  int* cnt = (int*)(ws + h_bytes + agg_bytes);
  int* offs = (int*)(ws + h_bytes + agg_bytes + cnt_bytes);
  int* rank = (int*)(ws + h_bytes + agg_bytes + cnt_bytes + offs_bytes);
  int* ug = rank;  // alias: rank dead after scatter_kernel
  int* ssrc = (int*)(ws + h_bytes + agg_bytes + cnt_bytes + offs_bytes + rank_bytes);
  (void)ug_bytes;

  hipMemsetAsync(cnt, 0, cnt_bytes, stream);
  hipMemsetAsync(h4, 0, h_bytes, stream);
  dim3 egrid((E_ + 255) / 256, L_);
  hist_kernel<<<egrid, 256, 0, stream>>>(dst_pos, cnt, rank);
  scan_kernel<<<L_, 1024, 0, stream>>>(cnt, offs);
  scatter_kernel<<<egrid, 256, 0, stream>>>(dst_pos, src, offs, rank, ssrc);
  hipMemsetAsync(ug, 0xFF, ug_bytes, stream);  // all -1 sentinels
  pad_fill_ug_k<<<(L_ * U_ + 255) / 256, 256, 0, stream>>>(cnt, offs, ssrc, ug);

  gene_init_k<<<(G_ * BC + 255) / 256, 256, 0, stream>>>(X, w_in, b_in, gene_map, h4);

  const int total_groups = EPL_ / 4;
  const int gwaves = (total_groups + GPW - 1) / GPW;
  const int gather_grid = (gwaves + 3) / 4;
  const int dense_grid = U_ * BC / 256;
  for (int li = 0; li < L_; ++li) {
    gather_k<<<gather_grid, 256, 0, stream>>>(h4, ug, ssrc, agg4, li);
    dense_k<<<dense_grid, 256, 0, stream>>>(agg4, W, bias, dst_unique, h4, li);
  }

  head_k<<<BC, 64, 0, stream>>>(h4, W_head, b_head, root_ids, out);
}